// Round 1
// baseline (239.255 us; speedup 1.0000x reference)
//
#include <hip/hip_runtime.h>

// PositionalEncoding: out[b,s,i] = x[b,s,i] + pe[s,i]
//   pe[s,i] = sin(s / 10000^((i/2)/D)) if i even, cos(...) if i odd
// B=8, S=4096, D=1024, fp32.
//
// R4: fused + batch-amortized, ONE kernel, no workspace.
// R1/R2's amortized attempt failed because the batch loop serialized
// (loads not hoisted, VGPR=28 -> 8 dependent HBM latencies/thread, 2 TB/s).
// Fix: load all 8 batch float4s into a named array BEFORE the pe
// computation (independent loads -> hoisted as a group), compute the
// 2x exp2 + 2x sincos chain (~300 VALU cycles) which simultaneously
// hides the load latency, then store all 8. Per thread: 8 KB of reads
// in flight -> one wave alone nearly covers HBM latency at 10 B/cyc/CU.
// Transcendentals amortized 8x vs per-element fused (~2 us aggregate).
// Removes: pe_table kernel launch + dependency, 16 MB table write,
// 134 MB of pe re-reads in the add kernel.

#define PE_B 8
#define PE_S 4096
#define PE_D 1024
#define ROW4 (PE_S * PE_D / 4)          // float4s per batch = 1,048,576
#define ROWF ((size_t)PE_S * PE_D)      // floats per batch = 4,194,304

typedef float v4f __attribute__((ext_vector_type(4)));

__global__ __launch_bounds__(256) void pe_fused_amortized(
    const float* __restrict__ x, float* __restrict__ out) {
    const int r = blockIdx.x * blockDim.x + threadIdx.x;   // 0 .. ROW4-1
    const int i = (r & (PE_D / 4 - 1)) * 4;                // elem index in row
    const int s = r >> 8;                                  // D/4 = 256

    // --- Phase 1: issue all 8 batch loads (independent -> hoisted) ---
    const float* xp = x + (size_t)r * 4;
    v4f xv[PE_B];
#pragma unroll
    for (int b = 0; b < PE_B; ++b)
        xv[b] = *(const v4f*)(xp + (size_t)b * ROWF);

    // --- Phase 2: pe for this (s, i..i+3) — hides the load latency ---
    const float pos = (float)s;
    const float c   = -13.287712379549449f / (float)PE_D;  // -log2(10000)/D
    const float k0  = (float)(i >> 1);
    const float a0  = pos * exp2f(k0 * c);
    const float a1  = pos * exp2f((k0 + 1.0f) * c);
    float s0, c0, s1, c1;
    sincosf(a0, &s0, &c0);
    sincosf(a1, &s1, &c1);
    const v4f pe = {s0, c0, s1, c1};     // even->sin, odd->cos

    // --- Phase 3: add + store all 8 ---
    float* op = out + (size_t)r * 4;
#pragma unroll
    for (int b = 0; b < PE_B; ++b)
        *(v4f*)(op + (size_t)b * ROWF) = xv[b] + pe;
}

extern "C" void kernel_launch(void* const* d_in, const int* in_sizes, int n_in,
                              void* d_out, int out_size, void* d_ws, size_t ws_size,
                              hipStream_t stream) {
    const float* x = (const float*)d_in[0];
    float* out = (float*)d_out;
    (void)d_ws; (void)ws_size;
    pe_fused_amortized<<<ROW4 / 256, 256, 0, stream>>>(x, out);
}

// Round 2
// 220.318 us; speedup vs baseline: 1.0860x; 1.0860x over previous
//
#include <hip/hip_runtime.h>

// PositionalEncoding: out[b,s,i] = x[b,s,i] + pe[s,i]
//   pe[s,i] = sin(s / 10000^((i/2)/D)) if i even, cos(...) if i odd
// B=8, S=4096, D=1024, fp32.
//
// R5: single fused per-element kernel (the old fallback, promoted).
// History:
//  - R1/R2/R4: batch-amortized (8 streams @16MB stride/thread) -> compiler
//    sinks loads (VGPR=28) AND the stride pattern TLB-thrashes: 2.2 TB/s
//    at 63% occupancy => ~4000-cycle effective latency. Pattern is dead.
//  - R0/R3: table + 3-stream add = ~80 us kernels total (add ~77 us at
//    ~3.7 TB/s incl. pe stream) + 148 us fixed harness overhead.
//  - Aggregate transcendental cost measured via R4 counters: 3.87% x 91 us
//    x8 ~= 28 us chip-wide, hideable under the 42 us 2-stream memory floor.
// So: pure contiguous copy-shape, one float4/thread, recompute pe in-regs.
// pe math kept bit-identical to the verified kernels (absmax 0.03125).

#define PE_B 8
#define PE_S 4096
#define PE_D 1024
#define ROW4 (PE_S * PE_D / 4)          // float4s per batch = 1,048,576

typedef float v4f __attribute__((ext_vector_type(4)));

__global__ __launch_bounds__(256) void pe_fused_kernel(
    const float* __restrict__ x, float* __restrict__ out) {
    const int idx = blockIdx.x * blockDim.x + threadIdx.x;   // 0 .. B*ROW4-1
    const int r   = idx & (ROW4 - 1);
    const int i   = (r & (PE_D / 4 - 1)) * 4;                // elem index in row
    const int s   = r >> 8;                                  // D/4 = 256

    const v4f v = *(const v4f*)(x + (size_t)idx * 4);

    const float pos = (float)s;
    const float c   = -13.287712379549449f / (float)PE_D;   // -log2(10000)/D
    const float k0  = (float)(i >> 1);
    const float a0  = pos * exp2f(k0 * c);
    const float a1  = pos * exp2f((k0 + 1.0f) * c);
    float s0, c0, s1, c1;
    sincosf(a0, &s0, &c0);
    sincosf(a1, &s1, &c1);
    const v4f pe = {s0, c0, s1, c1};     // even->sin, odd->cos

    *(v4f*)(out + (size_t)idx * 4) = v + pe;
}

extern "C" void kernel_launch(void* const* d_in, const int* in_sizes, int n_in,
                              void* d_out, int out_size, void* d_ws, size_t ws_size,
                              hipStream_t stream) {
    const float* x = (const float*)d_in[0];
    float* out = (float*)d_out;
    (void)d_ws; (void)ws_size;
    const int n4 = PE_B * ROW4;                       // 8,388,608 float4s
    pe_fused_kernel<<<n4 / 256, 256, 0, stream>>>(x, out);
}

// Round 3
// 216.255 us; speedup vs baseline: 1.1064x; 1.0188x over previous
//
#include <hip/hip_runtime.h>

// PositionalEncoding: out[b,s,i] = x[b,s,i] + pe[s,i]
//   pe[s,i] = sin(s / 10000^((i/2)/D)) if i even, cos(...) if i odd
// B=8, S=4096, D=1024, fp32.
//
// R6: fused kernel + branch-free HW sin/cos.
// History:
//  - batch-amortized (8 streams @16MB stride): TLB-thrash + compiler sinks
//    loads -> 2.2 TB/s. Dead pattern.
//  - table+add (R0): ~80 us of kernel time (3-stream add) + ~148 us fixed
//    harness fills.
//  - fused w/ libm sincosf (R5): ~72 us. Lanes in a wave span angles from
//    4095 rad to 1e-2 rad -> divergent fast/Payne-Hanek paths in OCML
//    sincos, wave executes both, stretching the load->store chain.
// Fix: compute the angle directly in REVOLUTIONS (fold 1/2pi into exp2),
// reduce with rintf + fmaf (single-rounding fract), feed v_sin_f32 /
// v_cos_f32 (f in [-0.5,0.5], branch-free, ~12 VALU ops total).
// Added error ~4e-4 abs, same order as existing exp2f angle rounding;
// absmax stays ~0.031. Nontemporal ld/st: both streams touched once.

#define PE_B 8
#define PE_S 4096
#define PE_D 1024
#define ROW4 (PE_S * PE_D / 4)          // float4s per batch = 1,048,576

typedef float v4f __attribute__((ext_vector_type(4)));

__global__ __launch_bounds__(256) void pe_fused_hwsin(
    const float* __restrict__ x, float* __restrict__ out) {
    const int idx = blockIdx.x * blockDim.x + threadIdx.x;   // 0 .. B*ROW4-1
    const int r   = idx & (ROW4 - 1);
    const int i   = (r & (PE_D / 4 - 1)) * 4;                // elem index in row
    const int s   = r >> 8;                                  // D/4 = 256

    const v4f v = __builtin_nontemporal_load((const v4f*)(x + (size_t)idx * 4));

    // rev = pos * 10000^(-k/D) / (2*pi)   (angle in revolutions)
    const float pos = (float)s;
    const float c   = -0.012976281620653759f;   // -log2(10000)/1024
    const float L   = -2.6514961294723187f;     // -log2(2*pi)
    const float k0  = (float)(i >> 1);
    const float w0  = __builtin_amdgcn_exp2f(fmaf(k0,        c, L));
    const float w1  = __builtin_amdgcn_exp2f(fmaf(k0 + 1.0f, c, L));
    // range-reduce to [-0.5, 0.5] revolutions; fma gives single-rounding fract
    const float f0  = fmaf(pos, w0, -rintf(pos * w0));
    const float f1  = fmaf(pos, w1, -rintf(pos * w1));
    const v4f pe = { __builtin_amdgcn_sinf(f0), __builtin_amdgcn_cosf(f0),
                     __builtin_amdgcn_sinf(f1), __builtin_amdgcn_cosf(f1) };

    __builtin_nontemporal_store(v + pe, (v4f*)(out + (size_t)idx * 4));
}

extern "C" void kernel_launch(void* const* d_in, const int* in_sizes, int n_in,
                              void* d_out, int out_size, void* d_ws, size_t ws_size,
                              hipStream_t stream) {
    const float* x = (const float*)d_in[0];
    float* out = (float*)d_out;
    (void)d_ws; (void)ws_size;
    const int n4 = PE_B * ROW4;                       // 8,388,608 float4s
    pe_fused_hwsin<<<n4 / 256, 256, 0, stream>>>(x, out);
}